// Round 1
// 1758.217 us; speedup vs baseline: 1.2677x; 1.2677x over previous
//
#include <hip/hip_runtime.h>
#include <math.h>

#define BB 256
#define SS 2048
#define EE 64
#define HH 128

typedef _Float16 half2_t __attribute__((ext_vector_type(2)));
typedef unsigned int uint2v __attribute__((ext_vector_type(2)));

#if defined(__has_builtin)
#if __has_builtin(__builtin_amdgcn_fdot2)
#define HAVE_FDOT2 1
#endif
#if __has_builtin(__builtin_amdgcn_update_dpp)
#define HAVE_DPP 1
#endif
#if __has_builtin(__builtin_amdgcn_permlane32_swap)
#define HAVE_PL32 1
#endif
#if __has_builtin(__builtin_amdgcn_exp2f)
#define EXP2F(x) __builtin_amdgcn_exp2f(x)
#else
#define EXP2F(x) exp2f(x)
#endif
#if __has_builtin(__builtin_amdgcn_rcpf)
#define RCPF(x) __builtin_amdgcn_rcpf(x)
#else
#define RCPF(x) (1.0f / (x))
#endif
#else
#define EXP2F(x) exp2f(x)
#define RCPF(x) (1.0f / (x))
#endif

__device__ __forceinline__ float dot2f(half2_t a, half2_t b, float c) {
#ifdef HAVE_FDOT2
    return __builtin_amdgcn_fdot2(a, b, c, false);
#else
    return c + (float)a.x * (float)b.x + (float)a.y * (float)b.y;
#endif
}

// quad_perm DPP: lane xor 1 / xor 2 within each quad (VALU pipe, no DS traffic)
__device__ __forceinline__ float dpp_xor1(float v) {
#ifdef HAVE_DPP
    int r = __builtin_amdgcn_update_dpp(0, __float_as_int(v), 0xB1, 0xF, 0xF, true);
    return __int_as_float(r);
#else
    return __shfl_xor(v, 1, 64);
#endif
}
__device__ __forceinline__ float dpp_xor2(float v) {
#ifdef HAVE_DPP
    int r = __builtin_amdgcn_update_dpp(0, __float_as_int(v), 0x4E, 0xF, 0xF, true);
    return __int_as_float(r);
#else
    return __shfl_xor(v, 2, 64);
#endif
}

// Cross-half exchange (lane l <-> l^32):
// lower lanes receive partner's `a`, upper lanes receive partner's `b`.
// v_permlane32_swap_b32: A'[i>=32] = B[i-32], B'[i<32] = A[i+32].
__device__ __forceinline__ float xhalf_recv(float a, float b, bool lower) {
#ifdef HAVE_PL32
    uint2v r = __builtin_amdgcn_permlane32_swap(__float_as_int(a), __float_as_int(b), false, false);
    return __int_as_float((int)(lower ? r.y : r.x));
#else
    float ra = __shfl_xor(a, 32, 64);
    float rb = __shfl_xor(b, 32, 64);
    return lower ? ra : rb;
#endif
}

// sigmoid via v_exp + v_rcp (no IEEE div sequence)
__device__ __forceinline__ float sigm_f(float x) {
    float e = EXP2F(-1.442695041f * x);
    return RCPF(1.0f + e);
}
// tanh(x) = 1 - 2/(1+exp2(2*log2e*x)); saturates cleanly at +-1, no clamp needed
__device__ __forceinline__ float tanh_f(float x) {
    float e = EXP2F(2.885390082f * x);
    return 1.0f - 2.0f * RCPF(1.0f + e);
}

// One block per batch element, 512 threads.
// 8-lane group = quad (4k..4k+3) U quad (4k+32..4k+35) of a wave; handles
// units u0 = 16*wave + 2k (lower quad) and u1 = u0+1 (upper quad).
// Lane owns k-slice [16*L, 16*L+16) of H where L = (t&3) + 4*((t>>5)&1).
// Per step per lane: 5 ds_read_b128 (h:2, c:2, x:1), 112 v_dot2,
// DPP/permlane reduce-scatter, ONE sigmoid per lane (gate ownership),
// quad-DPP combine; lane m==0 of each quad keeps the fp32 cell state.
__global__ __launch_bounds__(512, 2) void tlstm_fused8_kernel(
    const float* __restrict__ inputs,        // [B,S,E]
    const float* __restrict__ time_interval, // [B,S]
    const float* __restrict__ W_all,         // [4H,H]
    const float* __restrict__ b_all,         // [4H]
    const float* __restrict__ U_all,         // [4H,E]
    const float* __restrict__ b_u,           // [4H]
    const float* __restrict__ W_d,           // [H,H]
    const float* __restrict__ b_d,           // [H]
    const float* __restrict__ W_out,         // [1,H]
    const float* __restrict__ b_out,         // [1]
    float* __restrict__ out)                 // [B]
{
    const int b  = blockIdx.x;
    const int t  = threadIdx.x;
    const int wv = t >> 6;            // wave 0..7
    const int lh = (t >> 5) & 1;      // half of wave
    const int k  = (t >> 2) & 7;      // quad within half
    const int m  = t & 3;             // lane within quad
    const int L  = m + 4 * lh;        // slice owner index 0..7
    const bool lower = (lh == 0);

    const int un_base = 16 * wv + 2 * k;  // u0 of this group
    const int my_un   = un_base + lh;     // unit this quad combines

    __shared__ __align__(16) _Float16 sh_h[2][HH];
    __shared__ __align__(16) _Float16 sh_c[2][HH];
    __shared__ __align__(16) _Float16 sh_x[2][EE];
    __shared__ float sh_red[HH];

    // ---- weights into registers (fp16-packed) ----
    // wg[j][*]: W_all row (un_base + (j>>2)) + 128*(j&3), cols [16L,16L+16)
    // ug[j][*]: U_all same rows, cols [8L,8L+8)
    // wd[uu][*]: W_d row (un_base+uu), cols [16L,16L+16)
    half2_t wg[8][8];
    half2_t ug[8][4];
    half2_t wd[2][8];
    float   biasr, bd_r, wout_r;
    {
        #pragma unroll
        for (int uu = 0; uu < 2; ++uu) {
            #pragma unroll
            for (int q = 0; q < 4; ++q) {
                const int j   = q + 4 * uu;
                const int row = (un_base + uu) + 128 * q;
                const float4* pw = (const float4*)(W_all + (size_t)row * HH + 16 * L);
                #pragma unroll
                for (int i = 0; i < 4; ++i) {
                    float4 v = pw[i];
                    half2_t h0, h1;
                    h0.x = (_Float16)v.x; h0.y = (_Float16)v.y;
                    h1.x = (_Float16)v.z; h1.y = (_Float16)v.w;
                    wg[j][2*i]   = h0;
                    wg[j][2*i+1] = h1;
                }
                const float4* pu = (const float4*)(U_all + (size_t)row * EE + 8 * L);
                #pragma unroll
                for (int i = 0; i < 2; ++i) {
                    float4 v = pu[i];
                    half2_t h0, h1;
                    h0.x = (_Float16)v.x; h0.y = (_Float16)v.y;
                    h1.x = (_Float16)v.z; h1.y = (_Float16)v.w;
                    ug[j][2*i]   = h0;
                    ug[j][2*i+1] = h1;
                }
            }
            const int rowd = un_base + uu;
            const float4* pd = (const float4*)(W_d + (size_t)rowd * HH + 16 * L);
            #pragma unroll
            for (int i = 0; i < 4; ++i) {
                float4 v = pd[i];
                half2_t h0, h1;
                h0.x = (_Float16)v.x; h0.y = (_Float16)v.y;
                h1.x = (_Float16)v.z; h1.y = (_Float16)v.w;
                wd[uu][2*i]   = h0;
                wd[uu][2*i+1] = h1;
            }
        }
        const int row_own = my_un + 128 * m;   // gate row this lane owns post-reduction
        biasr  = b_all[row_own] + b_u[row_own];
        bd_r   = b_d[my_un];
        wout_r = W_out[my_un];
    }
    #pragma unroll
    for (int j = 0; j < 8; ++j) {
        #pragma unroll
        for (int i = 0; i < 8; ++i) asm volatile("" : "+v"(wg[j][i]));
        #pragma unroll
        for (int i = 0; i < 4; ++i) asm volatile("" : "+v"(ug[j][i]));
    }
    #pragma unroll
    for (int uu = 0; uu < 2; ++uu)
        #pragma unroll
        for (int i = 0; i < 8; ++i) asm volatile("" : "+v"(wd[uu][i]));

    const float* xb   = inputs + (size_t)b * SS * EE;
    const float* drow = time_interval + (size_t)b * SS;

    // ---- prologue: zero state buffer 0, prime x pipeline ----
    if (t < HH) { sh_h[0][t] = (_Float16)0.f; sh_c[0][t] = (_Float16)0.f; }
    float xcv = 0.f, xld = 0.f;
    if (t < EE) {
        sh_x[0][t] = (_Float16)xb[t];          // x[0]
        xcv = xb[EE + t];                       // x[1]
        xld = xb[2 * EE + t];                   // x[2]
    }
    float dv0 = drow[0], dv1 = drow[1], dv2 = drow[2];
    float hsum   = 0.f;
    float c_keep = 0.f;    // valid in lane m==0 of each quad (garbage elsewhere, unused)
    __syncthreads();

#define TLSTM_STEP(s, CUR, NXT)                                               \
    {                                                                         \
        if (t < EE) {                                                         \
            sh_x[NXT][t] = (_Float16)xcv;                                     \
            xcv = xld;                                                        \
            const int s3 = ((s) + 3 < SS) ? (s) + 3 : SS - 1;                 \
            xld = xb[(size_t)s3 * EE + t];                                    \
        }                                                                     \
        float4 hv0, hv1, cv0, cv1, xv0;                                       \
        {                                                                     \
            const float4* hp = (const float4*)(&sh_h[CUR][16 * L]);           \
            hv0 = hp[0]; hv1 = hp[1];                                         \
            const float4* cp = (const float4*)(&sh_c[CUR][16 * L]);           \
            cv0 = cp[0]; cv1 = cp[1];                                         \
            const float4* xp = (const float4*)(&sh_x[CUR][8 * L]);            \
            xv0 = xp[0];                                                      \
        }                                                                     \
        float a[8] = {0.f,0.f,0.f,0.f,0.f,0.f,0.f,0.f};                       \
        float ad0 = 0.f, ad1 = 0.f;                                           \
        {                                                                     \
            const half2_t* hh = (const half2_t*)&hv0;                         \
            _Pragma("unroll")                                                 \
            for (int p = 0; p < 4; ++p) {                                     \
                _Pragma("unroll")                                             \
                for (int j = 0; j < 8; ++j)                                   \
                    a[j] = dot2f(wg[j][p], hh[p], a[j]);                      \
            }                                                                 \
            hh = (const half2_t*)&hv1;                                        \
            _Pragma("unroll")                                                 \
            for (int p = 0; p < 4; ++p) {                                     \
                _Pragma("unroll")                                             \
                for (int j = 0; j < 8; ++j)                                   \
                    a[j] = dot2f(wg[j][4 + p], hh[p], a[j]);                  \
            }                                                                 \
            const half2_t* xh = (const half2_t*)&xv0;                         \
            _Pragma("unroll")                                                 \
            for (int p = 0; p < 4; ++p) {                                     \
                _Pragma("unroll")                                             \
                for (int j = 0; j < 8; ++j)                                   \
                    a[j] = dot2f(ug[j][p], xh[p], a[j]);                      \
            }                                                                 \
            const half2_t* ch = (const half2_t*)&cv0;                         \
            _Pragma("unroll")                                                 \
            for (int p = 0; p < 4; ++p) {                                     \
                ad0 = dot2f(wd[0][p], ch[p], ad0);                            \
                ad1 = dot2f(wd[1][p], ch[p], ad1);                            \
            }                                                                 \
            ch = (const half2_t*)&cv1;                                        \
            _Pragma("unroll")                                                 \
            for (int p = 0; p < 4; ++p) {                                     \
                ad0 = dot2f(wd[0][4 + p], ch[p], ad0);                        \
                ad1 = dot2f(wd[1][4 + p], ch[p], ad1);                        \
            }                                                                 \
        }                                                                     \
        /* reduce-scatter: lane ends owning gate j = m + 4*lh (fully summed) */\
        const bool oddl = (m & 1) != 0;                                       \
        const bool bit2 = (m & 2) != 0;                                       \
        float s0, s1, s2, s3v;                                                \
        {                                                                     \
            float snd, r;                                                     \
            snd = oddl ? a[0] : a[1]; r = dpp_xor1(snd);                      \
            s0 = (oddl ? a[1] : a[0]) + r;                                    \
            snd = oddl ? a[2] : a[3]; r = dpp_xor1(snd);                      \
            s1 = (oddl ? a[3] : a[2]) + r;                                    \
            snd = oddl ? a[4] : a[5]; r = dpp_xor1(snd);                      \
            s2 = (oddl ? a[5] : a[4]) + r;                                    \
            snd = oddl ? a[6] : a[7]; r = dpp_xor1(snd);                      \
            s3v = (oddl ? a[7] : a[6]) + r;                                   \
        }                                                                     \
        float u0v, u1v;                                                       \
        {                                                                     \
            float snd, r;                                                     \
            snd = bit2 ? s0 : s1; r = dpp_xor2(snd);                          \
            u0v = (bit2 ? s1 : s0) + r;                                       \
            snd = bit2 ? s2 : s3v; r = dpp_xor2(snd);                         \
            u1v = (bit2 ? s3v : s2) + r;                                      \
        }                                                                     \
        float g = (lower ? u0v : u1v) + xhalf_recv(u0v, u1v, lower);          \
        /* W_d dot: lower quads -> ad(u0), upper -> ad(u1), broadcast in quad */\
        float dd = (lower ? ad0 : ad1) + xhalf_recv(ad0, ad1, lower);         \
        dd += dpp_xor2(dd);                                                   \
        dd += dpp_xor1(dd);                                                   \
        /* lane-distributed activations: m=0:f 1:i 2:o(+cs1) 3:ct */          \
        float sg  = sigm_f(g + biasr);                                        \
        float cs1 = tanh_f(bd_r + dd);                                        \
        float sel1 = (m == 2) ? cs1 : sg;                                     \
        float sh2  = dpp_xor2(sel1);  /* m0<-cs1, m1<-sig(ct) */              \
        float sh2b = dpp_xor2(sg);    /* m0<-sig(o)           */              \
        float dm1  = dv0 - 1.0f;                                              \
        float cadj = __builtin_fmaf(sh2, dm1, c_keep);   /* m0: c+cs1*(d-1) */\
        float prod = sg * (oddl ? sh2 : cadj); /* m0: f*cadj, m1: i*ct */     \
        float cn   = prod + dpp_xor1(prod);    /* m0,m1: full c_new */        \
        float hn   = sh2b * tanh_f(cn);        /* m0: o*tanh(c_new) */        \
        c_keep = cn;                                                          \
        hsum  += hn;                                                          \
        if (m == 0) {                                                         \
            sh_c[NXT][my_un] = (_Float16)cn;                                  \
            sh_h[NXT][my_un] = (_Float16)hn;                                  \
        }                                                                     \
        dv0 = dv1; dv1 = dv2;                                                 \
        const int sd = ((s) + 3 < SS) ? (s) + 3 : SS - 1;                     \
        dv2 = drow[sd];                                                       \
        __syncthreads();                                                      \
    }

    for (int s = 0; s < SS; s += 2) {
        TLSTM_STEP(s,     0, 1)
        TLSTM_STEP(s + 1, 1, 0)
    }
#undef TLSTM_STEP

    // ---- output epilogue: out[b] = (sum_s h_s) . W_out + S*b_out ----
    if (m == 0) sh_red[my_un] = hsum * wout_r;
    __syncthreads();
    if (t == 0) {
        float acc = 0.f;
        for (int i = 0; i < HH; ++i) acc += sh_red[i];
        out[b] = acc + (float)SS * b_out[0];
    }
}

extern "C" void kernel_launch(void* const* d_in, const int* in_sizes, int n_in,
                              void* d_out, int out_size, void* d_ws, size_t ws_size,
                              hipStream_t stream) {
    const float* inputs        = (const float*)d_in[0];
    const float* time_interval = (const float*)d_in[1];
    const float* W_all         = (const float*)d_in[2];
    const float* b_all         = (const float*)d_in[3];
    const float* U_all         = (const float*)d_in[4];
    const float* b_u           = (const float*)d_in[5];
    const float* W_d           = (const float*)d_in[6];
    const float* b_d           = (const float*)d_in[7];
    const float* W_out         = (const float*)d_in[8];
    const float* b_out         = (const float*)d_in[9];
    float* out = (float*)d_out;

    tlstm_fused8_kernel<<<dim3(BB), dim3(512), 0, stream>>>(
        inputs, time_interval, W_all, b_all, U_all, b_u,
        W_d, b_d, W_out, b_out, out);
}